// Round 6
// baseline (794.333 us; speedup 1.0000x reference)
//
#include <hip/hip_runtime.h>
#include <math.h>

#define BN 4096   // batch per domain
#define DD 256    // feature dim
#define CC 31     // label classes

// ---------------- workspace layout ----------------
// [0]        double loss_acc
// [1]        double sum_sq
// [2..257]   double colsum[256]
// byte 2112: float aScale[32], bScale[32], negc[8], pad..., sq[8192]

// ---------------- kernel A: label column sums -> scale factors ----------------
__global__ void colscale_kernel(const float* __restrict__ s_label,
                                const float* __restrict__ t_label,
                                float* __restrict__ aScale,
                                float* __restrict__ bScale) {
  int c = blockIdx.x;           // 0..31 (31 = pad column)
  int t = threadIdx.x;
  double ss = 0.0, ts = 0.0;
  if (c < CC) {
    for (int r = t; r < BN; r += 256) {
      ss += (double)s_label[(size_t)r * CC + c];
      ts += (double)t_label[(size_t)r * CC + c];
    }
  }
  for (int off = 32; off; off >>= 1) {
    ss += __shfl_xor(ss, off);
    ts += __shfl_xor(ts, off);
  }
  __shared__ double rS[4], rT[4];
  int w = t >> 6, lane = t & 63;
  if (lane == 0) { rS[w] = ss; rT[w] = ts; }
  __syncthreads();
  if (t == 0) {
    double s_sum = rS[0] + rS[1] + rS[2] + rS[3];
    double t_sum = rT[0] + rT[1] + rT[2] + rT[3];
    bool valid = (c < CC) && (s_sum != 0.0) && (t_sum != 0.0);
    aScale[c] = valid ? (float)(1.0 / s_sum) : 0.f;
    bScale[c] = valid ? (float)(1.0 / t_sum) : 0.f;
  }
}

// ---------------- kernel B: per-row squared norms + total sum of squares ----------------
__global__ void rowsq_kernel(const float* __restrict__ source,
                             const float* __restrict__ target,
                             float* __restrict__ sqArr,
                             double* __restrict__ sumsq) {
  int row = blockIdx.x * 4 + (threadIdx.x >> 6);
  int lane = threadIdx.x & 63;
  const float* p = (row < BN) ? (source + (size_t)row * DD)
                              : (target + (size_t)(row - BN) * DD);
  float4 v = ((const float4*)p)[lane];
  float s = v.x * v.x + v.y * v.y + v.z * v.z + v.w * v.w;
  for (int off = 32; off; off >>= 1) s += __shfl_xor(s, off);
  __shared__ float red[4];
  if (lane == 0) { sqArr[row] = s; red[threadIdx.x >> 6] = s; }
  __syncthreads();
  if (threadIdx.x == 0)
    atomicAdd(sumsq, (double)(red[0] + red[1] + red[2] + red[3]));
}

// ---------------- kernel B2: column sums of total (for ||colsum||^2) ----------------
__global__ void colsum_kernel(const float* __restrict__ source,
                              const float* __restrict__ target,
                              double* __restrict__ colsum) {
  int d = threadIdx.x;         // 0..255
  int r0 = blockIdx.x * 256;   // 32 blocks * 256 rows
  float acc = 0.f;
  for (int r = r0; r < r0 + 256; ++r) {
    acc += (r < BN) ? source[(size_t)r * DD + d]
                    : target[(size_t)(r - BN) * DD + d];
  }
  atomicAdd(&colsum[d], (double)acc);
}

// ---------------- kernel C: bandwidth + exp coefficients ----------------
__global__ void bw_kernel(const double* __restrict__ sumsq,
                          const double* __restrict__ colsum,
                          float* __restrict__ negc) {
  __shared__ double red[256];
  int t = threadIdx.x;
  double cs = colsum[t];
  red[t] = cs * cs;
  __syncthreads();
  for (int s = 128; s; s >>= 1) {
    if (t < s) red[t] += red[t + s];
    __syncthreads();
  }
  if (t == 0) {
    double suml2 = 2.0 * 8192.0 * (*sumsq) - 2.0 * red[0];
    double bw = suml2 / (8192.0 * 8192.0 - 8192.0);
    bw = bw / 4.0;  // KERNEL_MUL^(KERNEL_NUM//2)
    for (int k = 0; k < 5; ++k)
      negc[k] = (float)(-1.0 / (bw * (double)(1 << k)));
  }
}

// ---------------- main fused kernel (symmetric: upper-triangle blocks only) ----
// Block (bi,bj), bi<=bj. 4 streams: SS, TT, ST1=(Si rows x Tj cols),
// ST2=(Sj rows x Ti cols). Block contribution:
//   w * [ wSS*Kss + wTT*Ktt - wST1*Kst1 - wST2*Kst2 ],  w = (bi==bj) ? 1 : 2.
// Diagonal blocks: ST1==ST2, so the formula reduces exactly to SS+TT-2*ST.
// LDS transposed [k][i], XOR-swizzled: dword addr = k*64 + (i ^ ((k&15)<<2)).
__global__ __launch_bounds__(256) void lmmd_main(
    const float* __restrict__ source, const float* __restrict__ target,
    const float* __restrict__ s_label, const float* __restrict__ t_label,
    const float* __restrict__ aScale, const float* __restrict__ bScale,
    const float* __restrict__ negc, const float* __restrict__ sqArr,
    double* __restrict__ accOut) {
  const int bi = blockIdx.x >> 6;
  const int bj = blockIdx.x & 63;
  if (bi > bj) return;  // block-uniform: no barrier divergence

  __shared__ __align__(16) float bufSi[32 * 64];
  __shared__ __align__(16) float bufSj[32 * 64];
  __shared__ __align__(16) float bufTi[32 * 64];
  __shared__ __align__(16) float bufTj[32 * 64];
  __shared__ double dred[256];

  const int t = threadIdx.x;
  const int tx = t & 15;
  const int ty = t >> 4;
  const int i0 = bi * 64;
  const int j0 = bj * 64;

  const int sc = t & 31;          // staging column (k)
  const int sr0 = (t >> 5) * 8;   // staging row base (i)

  float accSS[4][4] = {}, accTT[4][4] = {}, accST1[4][4] = {}, accST2[4][4] = {};
  float wSS[4][4] = {}, wTT[4][4] = {}, wST1[4][4] = {}, wST2[4][4] = {};

#define COMPUTE_CHUNK(A_SS, A_TT, A_ST1, A_ST2)                                \
  _Pragma("unroll")                                                            \
  for (int k = 0; k < 32; ++k) {                                               \
    const int swz = (k & 15) << 2;                                             \
    const float4 aS  = *(const float4*)&bufSi[k * 64 + ((ty * 4) ^ swz)];      \
    const float4 aT  = *(const float4*)&bufTi[k * 64 + ((ty * 4) ^ swz)];      \
    const float4 aS2 = *(const float4*)&bufSj[k * 64 + ((ty * 4) ^ swz)];      \
    const float4 bS  = *(const float4*)&bufSj[k * 64 + ((tx * 4) ^ swz)];      \
    const float4 bT  = *(const float4*)&bufTj[k * 64 + ((tx * 4) ^ swz)];      \
    const float4 bT2 = *(const float4*)&bufTi[k * 64 + ((tx * 4) ^ swz)];      \
    const float aSv[4]  = {aS.x, aS.y, aS.z, aS.w};                            \
    const float aTv[4]  = {aT.x, aT.y, aT.z, aT.w};                            \
    const float aS2v[4] = {aS2.x, aS2.y, aS2.z, aS2.w};                        \
    const float bSv[4]  = {bS.x, bS.y, bS.z, bS.w};                            \
    const float bTv[4]  = {bT.x, bT.y, bT.z, bT.w};                            \
    const float bT2v[4] = {bT2.x, bT2.y, bT2.z, bT2.w};                        \
    _Pragma("unroll")                                                          \
    for (int r = 0; r < 4; ++r) {                                              \
      _Pragma("unroll")                                                        \
      for (int q = 0; q < 4; ++q) {                                            \
        A_SS[r][q]  = fmaf(aSv[r],  bSv[q],  A_SS[r][q]);                      \
        A_TT[r][q]  = fmaf(aTv[r],  bTv[q],  A_TT[r][q]);                      \
        A_ST1[r][q] = fmaf(aSv[r],  bTv[q],  A_ST1[r][q]);                     \
        A_ST2[r][q] = fmaf(aS2v[r], bT2v[q], A_ST2[r][q]);                     \
      }                                                                        \
    }                                                                          \
  }

  // ---- feature phase: 8 chunks of K=32 ----
  for (int kb = 0; kb < DD; kb += 32) {
    __syncthreads();
#pragma unroll
    for (int ri = 0; ri < 8; ++ri) {
      const int r = sr0 + ri;
      const int off = sc * 64 + (r ^ ((sc & 15) << 2));
      bufSi[off] = source[(size_t)(i0 + r) * DD + kb + sc];
      bufSj[off] = source[(size_t)(j0 + r) * DD + kb + sc];
      bufTi[off] = target[(size_t)(i0 + r) * DD + kb + sc];
      bufTj[off] = target[(size_t)(j0 + r) * DD + kb + sc];
    }
    __syncthreads();
    COMPUTE_CHUNK(accSS, accTT, accST1, accST2)
  }

  // ---- label phase: one K=31 chunk (col 31 zero-padded) ----
  __syncthreads();
  {
    const float sA = (sc < CC) ? aScale[sc] : 0.f;
    const float sB = (sc < CC) ? bScale[sc] : 0.f;
#pragma unroll
    for (int ri = 0; ri < 8; ++ri) {
      const int r = sr0 + ri;
      const int off = sc * 64 + (r ^ ((sc & 15) << 2));
      float vSi = 0.f, vSj = 0.f, vTi = 0.f, vTj = 0.f;
      if (sc < CC) {
        vSi = s_label[(size_t)(i0 + r) * CC + sc] * sA;
        vSj = s_label[(size_t)(j0 + r) * CC + sc] * sA;
        vTi = t_label[(size_t)(i0 + r) * CC + sc] * sB;
        vTj = t_label[(size_t)(j0 + r) * CC + sc] * sB;
      }
      bufSi[off] = vSi; bufSj[off] = vSj; bufTi[off] = vTi; bufTj[off] = vTj;
    }
    __syncthreads();
    COMPUTE_CHUNK(wSS, wTT, wST1, wST2)
  }

  // ---- epilogue: kernels + weighted sum ----
  const float nc0 = negc[0], nc1 = negc[1], nc2 = negc[2], nc3 = negc[3],
              nc4 = negc[4];
  // sq lookups (S = sqArr[0..BN), T = sqArr[BN..2BN))
  float sqS_ir[4], sqS_jc[4], sqS_jr[4], sqT_jc[4], sqT_ir[4], sqT_ic[4];
#pragma unroll
  for (int r = 0; r < 4; ++r) {
    sqS_ir[r] = sqArr[i0 + ty * 4 + r];        // S rows of tile bi
    sqS_jr[r] = sqArr[j0 + ty * 4 + r];        // S rows of tile bj (ST2)
    sqT_ir[r] = sqArr[BN + i0 + ty * 4 + r];   // T rows of tile bi
  }
#pragma unroll
  for (int q = 0; q < 4; ++q) {
    sqS_jc[q] = sqArr[j0 + tx * 4 + q];        // S cols of tile bj
    sqT_jc[q] = sqArr[BN + j0 + tx * 4 + q];   // T cols of tile bj
    sqT_ic[q] = sqArr[BN + i0 + tx * 4 + q];   // T cols of tile bi (ST2)
  }
  double tsum = 0.0;
#pragma unroll
  for (int r = 0; r < 4; ++r) {
#pragma unroll
    for (int q = 0; q < 4; ++q) {
      const float l2ss  = sqS_ir[r] + sqS_jc[q] - 2.f * accSS[r][q];
      const float l2tt  = sqT_ir[r] + sqT_jc[q] - 2.f * accTT[r][q];
      const float l2st1 = sqS_ir[r] + sqT_jc[q] - 2.f * accST1[r][q];
      const float l2st2 = sqS_jr[r] + sqT_ic[q] - 2.f * accST2[r][q];
      const float Kss  = __expf(l2ss * nc0) + __expf(l2ss * nc1) +
                         __expf(l2ss * nc2) + __expf(l2ss * nc3) +
                         __expf(l2ss * nc4);
      const float Ktt  = __expf(l2tt * nc0) + __expf(l2tt * nc1) +
                         __expf(l2tt * nc2) + __expf(l2tt * nc3) +
                         __expf(l2tt * nc4);
      const float Kst1 = __expf(l2st1 * nc0) + __expf(l2st1 * nc1) +
                         __expf(l2st1 * nc2) + __expf(l2st1 * nc3) +
                         __expf(l2st1 * nc4);
      const float Kst2 = __expf(l2st2 * nc0) + __expf(l2st2 * nc1) +
                         __expf(l2st2 * nc2) + __expf(l2st2 * nc3) +
                         __expf(l2st2 * nc4);
      tsum += (double)(wSS[r][q] * Kss + wTT[r][q] * Ktt -
                       wST1[r][q] * Kst1 - wST2[r][q] * Kst2);
    }
  }
  if (bi != bj) tsum *= 2.0;  // off-diagonal pair covers (bi,bj) and (bj,bi)
  dred[t] = tsum;
  __syncthreads();
  for (int s = 128; s; s >>= 1) {
    if (t < s) dred[t] += dred[t + s];
    __syncthreads();
  }
  if (t == 0) atomicAdd(accOut, dred[0]);
}

// ---------------- finalize ----------------
__global__ void finalize_kernel(const double* __restrict__ acc,
                                float* __restrict__ out) {
  out[0] = (float)acc[0];
}

extern "C" void kernel_launch(void* const* d_in, const int* in_sizes, int n_in,
                              void* d_out, int out_size, void* d_ws,
                              size_t ws_size, hipStream_t stream) {
  const float* source = (const float*)d_in[0];
  const float* target = (const float*)d_in[1];
  const float* s_label = (const float*)d_in[2];
  const float* t_label = (const float*)d_in[3];

  double* acc = (double*)d_ws;     // [0] loss
  double* sumsq = acc + 1;         // [1]
  double* colsum = acc + 2;        // [2..257]
  float* fbase = (float*)((char*)d_ws + 2112);
  float* aScale = fbase;           // 32
  float* bScale = fbase + 32;      // 32
  float* negc = fbase + 64;        // 8
  float* sqArr = fbase + 128;      // 8192

  hipMemsetAsync(d_ws, 0, 2112, stream);
  colscale_kernel<<<32, 256, 0, stream>>>(s_label, t_label, aScale, bScale);
  rowsq_kernel<<<2048, 256, 0, stream>>>(source, target, sqArr, sumsq);
  colsum_kernel<<<32, 256, 0, stream>>>(source, target, colsum);
  bw_kernel<<<1, 256, 0, stream>>>(sumsq, colsum, negc);
  lmmd_main<<<4096, 256, 0, stream>>>(source, target, s_label, t_label, aScale,
                                      bScale, negc, sqArr, acc);
  finalize_kernel<<<1, 1, 0, stream>>>(acc, (float*)d_out);
}

// Round 10
// 248.123 us; speedup vs baseline: 3.2014x; 3.2014x over previous
//
#include <hip/hip_runtime.h>
#include <hip/hip_bf16.h>
#include <math.h>

#define BN 4096   // batch per domain
#define DD 256    // feature dim
#define CC 31     // label classes
#define KP 352    // packed k per row: 256 feat + 32 augA + 32 augB + 32 label
#define AUGA 256
#define AUGB 288
#define LABK 320

typedef __attribute__((ext_vector_type(8))) short bf16x8;
typedef __attribute__((ext_vector_type(4))) float f32x4;

static __device__ inline unsigned short f2bf(float v) {
  __hip_bfloat16 h = __float2bfloat16(v);
  union { __hip_bfloat16 h; unsigned short u; } cv;
  cv.h = h;
  return cv.u;
}
static __device__ inline float bf2f(unsigned short u) {
  return __uint_as_float(((unsigned int)u) << 16);
}

// ---------------- workspace layout ----------------
// [0]        double loss_acc
// [1]        double sum_sq
// [2..257]   double colsum[256]
// byte 2112: float aScale[32], bScale[32], negc[8]
// byte 4096: unsigned short pack[8192][352]   (~5.8 MB)

// ---------------- kernel A: label column sums -> scale factors ----------------
__global__ void colscale_kernel(const float* __restrict__ s_label,
                                const float* __restrict__ t_label,
                                float* __restrict__ aScale,
                                float* __restrict__ bScale) {
  int c = blockIdx.x;  // 0..31 (31 = pad column)
  int t = threadIdx.x;
  double ss = 0.0, ts = 0.0;
  if (c < CC) {
    for (int r = t; r < BN; r += 256) {
      ss += (double)s_label[(size_t)r * CC + c];
      ts += (double)t_label[(size_t)r * CC + c];
    }
  }
  for (int off = 32; off; off >>= 1) {
    ss += __shfl_xor(ss, off);
    ts += __shfl_xor(ts, off);
  }
  __shared__ double rS[4], rT[4];
  int w = t >> 6, lane = t & 63;
  if (lane == 0) { rS[w] = ss; rT[w] = ts; }
  __syncthreads();
  if (t == 0) {
    double s_sum = rS[0] + rS[1] + rS[2] + rS[3];
    double t_sum = rT[0] + rT[1] + rT[2] + rT[3];
    bool valid = (c < CC) && (s_sum != 0.0) && (t_sum != 0.0);
    aScale[c] = valid ? (float)(1.0 / s_sum) : 0.f;
    bScale[c] = valid ? (float)(1.0 / t_sum) : 0.f;
  }
}

// ---------------- kernel B: total sum of squares (fp32, for bw) ----------------
__global__ void sumsq_kernel(const float* __restrict__ source,
                             const float* __restrict__ target,
                             double* __restrict__ sumsq) {
  int row = blockIdx.x * 4 + (threadIdx.x >> 6);
  int lane = threadIdx.x & 63;
  const float* p = (row < BN) ? (source + (size_t)row * DD)
                              : (target + (size_t)(row - BN) * DD);
  float4 v = ((const float4*)p)[lane];
  float s = v.x * v.x + v.y * v.y + v.z * v.z + v.w * v.w;
  for (int off = 32; off; off >>= 1) s += __shfl_xor(s, off);
  __shared__ float red[4];
  if (lane == 0) red[threadIdx.x >> 6] = s;
  __syncthreads();
  if (threadIdx.x == 0)
    atomicAdd(sumsq, (double)(red[0] + red[1] + red[2] + red[3]));
}

// ---------------- kernel B2: column sums (for ||colsum||^2 in bw) ----------------
__global__ void colsum_kernel(const float* __restrict__ source,
                              const float* __restrict__ target,
                              double* __restrict__ colsum) {
  int d = threadIdx.x;        // 0..255
  int r0 = blockIdx.x * 256;  // 32 blocks * 256 rows
  float acc = 0.f;
  for (int r = r0; r < r0 + 256; ++r) {
    acc += (r < BN) ? source[(size_t)r * DD + d]
                    : target[(size_t)(r - BN) * DD + d];
  }
  atomicAdd(&colsum[d], (double)acc);
}

// ---------------- kernel C: bandwidth + exp coefficients ----------------
__global__ void bw_kernel(const double* __restrict__ sumsq,
                          const double* __restrict__ colsum,
                          float* __restrict__ negc) {
  __shared__ double red[256];
  int t = threadIdx.x;
  double cs = colsum[t];
  red[t] = cs * cs;
  __syncthreads();
  for (int s = 128; s; s >>= 1) {
    if (t < s) red[t] += red[t + s];
    __syncthreads();
  }
  if (t == 0) {
    double suml2 = 2.0 * 8192.0 * (*sumsq) - 2.0 * red[0];
    double bw = suml2 / (8192.0 * 8192.0 - 8192.0);
    bw = bw / 4.0;  // KERNEL_MUL^(KERNEL_NUM//2)
    for (int k = 0; k < 5; ++k)
      negc[k] = (float)(-1.0 / (bw * (double)(1 << k)));
  }
}

// ---------------- pack kernel: fp32 -> bf16 rows with aug + labels ----------------
// Row vr (0..8191): S rows 0..4095 (source), T rows 4096..8191 (target).
// pack[vr][0..255]   = bf16(x)
// pack[vr][256..287] = augA = [h, lo, 1, 1, 0...]   (h+lo ~ -0.5*sum(x_bf16^2))
// pack[vr][288..319] = augB = [1, 1, h, lo, 0...]
// pack[vr][320..351] = scaled label vec (31 + pad0)
// => dot(A_row_i, B_row_j) with A using augA, B using augB:
//    acc = sum(x_i x_j) - 0.5 sq_i - 0.5 sq_j  =>  l2 = -2*acc. Layout-proof.
__global__ void pack_kernel(const float* __restrict__ source,
                            const float* __restrict__ target,
                            const float* __restrict__ s_label,
                            const float* __restrict__ t_label,
                            const float* __restrict__ aScale,
                            const float* __restrict__ bScale,
                            unsigned short* __restrict__ pack) {
  const int vr = blockIdx.x;  // 0..8191
  const int l = threadIdx.x;  // 0..63
  const bool isS = (vr < BN);
  const float* xp = isS ? (source + (size_t)vr * DD)
                        : (target + (size_t)(vr - BN) * DD);
  float4 v = ((const float4*)xp)[l];
  unsigned short ub[4] = {f2bf(v.x), f2bf(v.y), f2bf(v.z), f2bf(v.w)};
  float f[4];
#pragma unroll
  for (int e = 0; e < 4; ++e) f[e] = bf2f(ub[e]);
  float sq = f[0] * f[0] + f[1] * f[1] + f[2] * f[2] + f[3] * f[3];
#pragma unroll
  for (int off = 32; off; off >>= 1) sq += __shfl_xor(sq, off);

  const size_t rb = (size_t)vr * KP;
  *(short4*)&pack[rb + l * 4] =
      make_short4((short)ub[0], (short)ub[1], (short)ub[2], (short)ub[3]);

  if (l < 8) {
    const unsigned short one = f2bf(1.0f);
    const float hs = -0.5f * sq;
    const unsigned short hh = f2bf(hs);
    const unsigned short lo = f2bf(hs - bf2f(hh));
    const int c0 = l * 4;
    unsigned short a_aug[4], b_aug[4], labv[4];
#pragma unroll
    for (int e = 0; e < 4; ++e) {
      const int c = c0 + e;
      a_aug[e] = (c == 0) ? hh : (c == 1) ? lo : (c <= 3) ? one : (unsigned short)0;
      b_aug[e] = (c <= 1) ? one : (c == 2) ? hh : (c == 3) ? lo : (unsigned short)0;
      float lv = 0.f;
      if (c < CC) {
        lv = isS ? s_label[(size_t)vr * CC + c] * aScale[c]
                 : t_label[(size_t)(vr - BN) * CC + c] * bScale[c];
      }
      labv[e] = f2bf(lv);
    }
    *(short4*)&pack[rb + AUGA + c0] = make_short4(
        (short)a_aug[0], (short)a_aug[1], (short)a_aug[2], (short)a_aug[3]);
    *(short4*)&pack[rb + AUGB + c0] = make_short4(
        (short)b_aug[0], (short)b_aug[1], (short)b_aug[2], (short)b_aug[3]);
    *(short4*)&pack[rb + LABK + c0] = make_short4(
        (short)labv[0], (short)labv[1], (short)labv[2], (short)labv[3]);
  }
}

// ---------------- main fused kernel (MFMA, no LDS staging, no barriers) --------
// 64x64 tile per block, 4 waves; wave w owns rows [w*16, w*16+16), all 64 cols.
// 3 streams (SS, TT, ST) x 4 col-subtiles; 10 K-chunks of 32 (8 feat + aug + lab).
// l2 = -2*acc is co-located with its weight w in the same register -> epilogue is
// elementwise + global sum: invariant to MFMA M/N/lane layout details.
__global__ __launch_bounds__(256) void lmmd_main(
    const unsigned short* __restrict__ pack, const float* __restrict__ negc,
    double* __restrict__ accOut) {
  const int t = threadIdx.x;
  const int lane = t & 63;
  const int wv = t >> 6;
  const int bi = blockIdx.x >> 6;
  const int bj = blockIdx.x & 63;
  const int r15 = lane & 15;
  const int kb0 = (lane >> 4) * 8;

  const int rowSi = (bi * 64 + wv * 16 + r15) * KP;
  const int rowTi = rowSi + BN * KP;
  int colS[4], colT[4];
#pragma unroll
  for (int n = 0; n < 4; ++n) {
    colS[n] = (bj * 64 + n * 16 + r15) * KP;
    colT[n] = colS[n] + BN * KP;
  }

  f32x4 aSS[4], aTT[4], aST[4], wSS[4], wTT[4], wST[4];
#pragma unroll
  for (int n = 0; n < 4; ++n) {
    aSS[n] = {0.f, 0.f, 0.f, 0.f};
    aTT[n] = {0.f, 0.f, 0.f, 0.f};
    aST[n] = {0.f, 0.f, 0.f, 0.f};
    wSS[n] = {0.f, 0.f, 0.f, 0.f};
    wTT[n] = {0.f, 0.f, 0.f, 0.f};
    wST[n] = {0.f, 0.f, 0.f, 0.f};
  }

  // 8 feature chunks (A and B read the same k-range)
#pragma unroll
  for (int c = 0; c < 8; ++c) {
    const int ko = c * 32 + kb0;
    const bf16x8 aS = *(const bf16x8*)&pack[rowSi + ko];
    const bf16x8 aT = *(const bf16x8*)&pack[rowTi + ko];
#pragma unroll
    for (int n = 0; n < 4; ++n) {
      const bf16x8 bS = *(const bf16x8*)&pack[colS[n] + ko];
      const bf16x8 bT = *(const bf16x8*)&pack[colT[n] + ko];
      aSS[n] = __builtin_amdgcn_mfma_f32_16x16x32_bf16(aS, bS, aSS[n], 0, 0, 0);
      aTT[n] = __builtin_amdgcn_mfma_f32_16x16x32_bf16(aT, bT, aTT[n], 0, 0, 0);
      aST[n] = __builtin_amdgcn_mfma_f32_16x16x32_bf16(aS, bT, aST[n], 0, 0, 0);
    }
  }
  // aug chunk: A-side reads augA, B-side reads augB
  {
    const int koA = AUGA + kb0;
    const int koB = AUGB + kb0;
    const bf16x8 aS = *(const bf16x8*)&pack[rowSi + koA];
    const bf16x8 aT = *(const bf16x8*)&pack[rowTi + koA];
#pragma unroll
    for (int n = 0; n < 4; ++n) {
      const bf16x8 bS = *(const bf16x8*)&pack[colS[n] + koB];
      const bf16x8 bT = *(const bf16x8*)&pack[colT[n] + koB];
      aSS[n] = __builtin_amdgcn_mfma_f32_16x16x32_bf16(aS, bS, aSS[n], 0, 0, 0);
      aTT[n] = __builtin_amdgcn_mfma_f32_16x16x32_bf16(aT, bT, aTT[n], 0, 0, 0);
      aST[n] = __builtin_amdgcn_mfma_f32_16x16x32_bf16(aS, bT, aST[n], 0, 0, 0);
    }
  }
  // label chunk -> weight accumulators
  {
    const int ko = LABK + kb0;
    const bf16x8 aS = *(const bf16x8*)&pack[rowSi + ko];
    const bf16x8 aT = *(const bf16x8*)&pack[rowTi + ko];
#pragma unroll
    for (int n = 0; n < 4; ++n) {
      const bf16x8 bS = *(const bf16x8*)&pack[colS[n] + ko];
      const bf16x8 bT = *(const bf16x8*)&pack[colT[n] + ko];
      wSS[n] = __builtin_amdgcn_mfma_f32_16x16x32_bf16(aS, bS, wSS[n], 0, 0, 0);
      wTT[n] = __builtin_amdgcn_mfma_f32_16x16x32_bf16(aT, bT, wTT[n], 0, 0, 0);
      wST[n] = __builtin_amdgcn_mfma_f32_16x16x32_bf16(aS, bT, wST[n], 0, 0, 0);
    }
  }

  // epilogue: l2 = -2*acc, 5-kernel exp sum, weighted combine (all co-located)
  const float nc0 = negc[0], nc1 = negc[1], nc2 = negc[2], nc3 = negc[3],
              nc4 = negc[4];
  double tsum = 0.0;
#pragma unroll
  for (int n = 0; n < 4; ++n) {
#pragma unroll
    for (int e = 0; e < 4; ++e) {
      const float l2ss = -2.f * aSS[n][e];
      const float l2tt = -2.f * aTT[n][e];
      const float l2st = -2.f * aST[n][e];
      const float Kss = __expf(l2ss * nc0) + __expf(l2ss * nc1) +
                        __expf(l2ss * nc2) + __expf(l2ss * nc3) +
                        __expf(l2ss * nc4);
      const float Ktt = __expf(l2tt * nc0) + __expf(l2tt * nc1) +
                        __expf(l2tt * nc2) + __expf(l2tt * nc3) +
                        __expf(l2tt * nc4);
      const float Kst = __expf(l2st * nc0) + __expf(l2st * nc1) +
                        __expf(l2st * nc2) + __expf(l2st * nc3) +
                        __expf(l2st * nc4);
      tsum += (double)(wSS[n][e] * Kss + wTT[n][e] * Ktt -
                       2.f * wST[n][e] * Kst);
    }
  }
  __shared__ double dred[256];
  dred[t] = tsum;
  __syncthreads();
  for (int s = 128; s; s >>= 1) {
    if (t < s) dred[t] += dred[t + s];
    __syncthreads();
  }
  if (t == 0) atomicAdd(accOut, dred[0]);
}

// ---------------- finalize ----------------
__global__ void finalize_kernel(const double* __restrict__ acc,
                                float* __restrict__ out) {
  out[0] = (float)acc[0];
}

extern "C" void kernel_launch(void* const* d_in, const int* in_sizes, int n_in,
                              void* d_out, int out_size, void* d_ws,
                              size_t ws_size, hipStream_t stream) {
  const float* source = (const float*)d_in[0];
  const float* target = (const float*)d_in[1];
  const float* s_label = (const float*)d_in[2];
  const float* t_label = (const float*)d_in[3];

  double* acc = (double*)d_ws;  // [0] loss
  double* sumsq = acc + 1;      // [1]
  double* colsum = acc + 2;     // [2..257]
  float* fbase = (float*)((char*)d_ws + 2112);
  float* aScale = fbase;        // 32
  float* bScale = fbase + 32;   // 32
  float* negc = fbase + 64;     // 8
  unsigned short* pack = (unsigned short*)((char*)d_ws + 4096);  // 8192*352

  hipMemsetAsync(d_ws, 0, 2112, stream);
  colscale_kernel<<<32, 256, 0, stream>>>(s_label, t_label, aScale, bScale);
  sumsq_kernel<<<2048, 256, 0, stream>>>(source, target, sumsq);
  colsum_kernel<<<32, 256, 0, stream>>>(source, target, colsum);
  bw_kernel<<<1, 256, 0, stream>>>(sumsq, colsum, negc);
  pack_kernel<<<8192, 64, 0, stream>>>(source, target, s_label, t_label,
                                       aScale, bScale, pack);
  lmmd_main<<<4096, 256, 0, stream>>>(pack, negc, acc);
  finalize_kernel<<<1, 1, 0, stream>>>(acc, (float*)d_out);
}

// Round 11
// 171.421 us; speedup vs baseline: 4.6338x; 1.4475x over previous
//
#include <hip/hip_runtime.h>
#include <hip/hip_bf16.h>
#include <math.h>

#define BN 4096   // batch per domain
#define DD 256    // feature dim
#define CC 31     // label classes
#define KP 352    // packed k per row: 256 feat + 32 augA + 32 augB + 32 label
#define AUGA 256
#define AUGB 288
#define LABK 320

typedef __attribute__((ext_vector_type(8))) short bf16x8;
typedef __attribute__((ext_vector_type(4))) float f32x4;

static __device__ inline unsigned short f2bf(float v) {
  __hip_bfloat16 h = __float2bfloat16(v);
  union { __hip_bfloat16 h; unsigned short u; } cv;
  cv.h = h;
  return cv.u;
}
static __device__ inline float bf2f(unsigned short u) {
  return __uint_as_float(((unsigned int)u) << 16);
}

// ---------------- workspace layout ----------------
// [0]        double loss_acc
// [1]        double sum_sq
// [2..257]   double colsum[256]
// byte 2112: float aScale[32], bScale[32], negc[8]
// byte 4096: unsigned short pack[8192][352]   (~5.8 MB)

// ---------------- kernel A: label column sums -> scale factors ----------------
__global__ void colscale_kernel(const float* __restrict__ s_label,
                                const float* __restrict__ t_label,
                                float* __restrict__ aScale,
                                float* __restrict__ bScale) {
  int c = blockIdx.x;  // 0..31 (31 = pad column)
  int t = threadIdx.x;
  double ss = 0.0, ts = 0.0;
  if (c < CC) {
    for (int r = t; r < BN; r += 256) {
      ss += (double)s_label[(size_t)r * CC + c];
      ts += (double)t_label[(size_t)r * CC + c];
    }
  }
  for (int off = 32; off; off >>= 1) {
    ss += __shfl_xor(ss, off);
    ts += __shfl_xor(ts, off);
  }
  __shared__ double rS[4], rT[4];
  int w = t >> 6, lane = t & 63;
  if (lane == 0) { rS[w] = ss; rT[w] = ts; }
  __syncthreads();
  if (t == 0) {
    double s_sum = rS[0] + rS[1] + rS[2] + rS[3];
    double t_sum = rT[0] + rT[1] + rT[2] + rT[3];
    bool valid = (c < CC) && (s_sum != 0.0) && (t_sum != 0.0);
    aScale[c] = valid ? (float)(1.0 / s_sum) : 0.f;
    bScale[c] = valid ? (float)(1.0 / t_sum) : 0.f;
  }
}

// ---------------- fused stats: column sums + total sum of squares ----------------
// 256 blocks x 256 threads; block b handles rows [b*32, b*32+32), thread d = col d.
__global__ void stats_kernel(const float* __restrict__ source,
                             const float* __restrict__ target,
                             double* __restrict__ colsum,
                             double* __restrict__ sumsq) {
  const int d = threadIdx.x;
  const int r0 = blockIdx.x * 32;
  float cs = 0.f, sq = 0.f;
  for (int r = r0; r < r0 + 32; ++r) {
    const float v = (r < BN) ? source[(size_t)r * DD + d]
                             : target[(size_t)(r - BN) * DD + d];
    cs += v;
    sq += v * v;
  }
  atomicAdd(&colsum[d], (double)cs);
  __shared__ float red[256];
  red[d] = sq;
  __syncthreads();
  for (int s = 128; s; s >>= 1) {
    if (d < s) red[d] += red[d + s];
    __syncthreads();
  }
  if (d == 0) atomicAdd(sumsq, (double)red[0]);
}

// ---------------- kernel C: bandwidth + exp coefficients ----------------
__global__ void bw_kernel(const double* __restrict__ sumsq,
                          const double* __restrict__ colsum,
                          float* __restrict__ negc) {
  __shared__ double red[256];
  int t = threadIdx.x;
  double cs = colsum[t];
  red[t] = cs * cs;
  __syncthreads();
  for (int s = 128; s; s >>= 1) {
    if (t < s) red[t] += red[t + s];
    __syncthreads();
  }
  if (t == 0) {
    double suml2 = 2.0 * 8192.0 * (*sumsq) - 2.0 * red[0];
    double bw = suml2 / (8192.0 * 8192.0 - 8192.0);
    bw = bw / 4.0;  // KERNEL_MUL^(KERNEL_NUM//2)
    for (int k = 0; k < 5; ++k)
      negc[k] = (float)(-1.0 / (bw * (double)(1 << k)));
  }
}

// ---------------- pack kernel: fp32 -> bf16 rows with aug + labels ----------------
// Row vr (0..8191): S rows 0..4095 (source), T rows 4096..8191 (target).
// pack[vr][0..255]   = bf16(x)
// pack[vr][256..287] = augA = [h, lo, 1, 1, 0...]   (h+lo ~ -0.5*sum(x_bf16^2))
// pack[vr][288..319] = augB = [1, 1, h, lo, 0...]
// pack[vr][320..351] = scaled label vec (31 + pad0)
// => dot(A_row_i, B_row_j) with A using augA, B using augB:
//    acc = sum(x_i x_j) - 0.5 sq_i - 0.5 sq_j  =>  l2 = -2*acc. Layout-proof.
__global__ void pack_kernel(const float* __restrict__ source,
                            const float* __restrict__ target,
                            const float* __restrict__ s_label,
                            const float* __restrict__ t_label,
                            const float* __restrict__ aScale,
                            const float* __restrict__ bScale,
                            unsigned short* __restrict__ pack) {
  const int vr = blockIdx.x;  // 0..8191
  const int l = threadIdx.x;  // 0..63
  const bool isS = (vr < BN);
  const float* xp = isS ? (source + (size_t)vr * DD)
                        : (target + (size_t)(vr - BN) * DD);
  float4 v = ((const float4*)xp)[l];
  unsigned short ub[4] = {f2bf(v.x), f2bf(v.y), f2bf(v.z), f2bf(v.w)};
  float f[4];
#pragma unroll
  for (int e = 0; e < 4; ++e) f[e] = bf2f(ub[e]);
  float sq = f[0] * f[0] + f[1] * f[1] + f[2] * f[2] + f[3] * f[3];
#pragma unroll
  for (int off = 32; off; off >>= 1) sq += __shfl_xor(sq, off);

  const size_t rb = (size_t)vr * KP;
  *(short4*)&pack[rb + l * 4] =
      make_short4((short)ub[0], (short)ub[1], (short)ub[2], (short)ub[3]);

  if (l < 8) {
    const unsigned short one = f2bf(1.0f);
    const float hs = -0.5f * sq;
    const unsigned short hh = f2bf(hs);
    const unsigned short lo = f2bf(hs - bf2f(hh));
    const int c0 = l * 4;
    unsigned short a_aug[4], b_aug[4], labv[4];
#pragma unroll
    for (int e = 0; e < 4; ++e) {
      const int c = c0 + e;
      a_aug[e] = (c == 0) ? hh : (c == 1) ? lo : (c <= 3) ? one : (unsigned short)0;
      b_aug[e] = (c <= 1) ? one : (c == 2) ? hh : (c == 3) ? lo : (unsigned short)0;
      float lv = 0.f;
      if (c < CC) {
        lv = isS ? s_label[(size_t)vr * CC + c] * aScale[c]
                 : t_label[(size_t)(vr - BN) * CC + c] * bScale[c];
      }
      labv[e] = f2bf(lv);
    }
    *(short4*)&pack[rb + AUGA + c0] = make_short4(
        (short)a_aug[0], (short)a_aug[1], (short)a_aug[2], (short)a_aug[3]);
    *(short4*)&pack[rb + AUGB + c0] = make_short4(
        (short)b_aug[0], (short)b_aug[1], (short)b_aug[2], (short)b_aug[3]);
    *(short4*)&pack[rb + LABK + c0] = make_short4(
        (short)labv[0], (short)labv[1], (short)labv[2], (short)labv[3]);
  }
}

// ---------------- main fused kernel (MFMA + LDS-staged B, double-buffered) ----
// 64x64 tile per block, 4 waves; wave w owns rows [w*16,w*16+16), all 64 cols.
// B-panel (64 S-cols + 64 T-cols) staged into LDS once per K-chunk (vs 4x
// redundant global reads in R10's version). 10 chunks of K=32 (8 feat, aug, lab).
// ds_read pattern: 64 lanes cover 256 distinct words -> conflict-free.
// Buffer lifecycle: write buf[(c+1)&1] in iter c, read buf[c&1]; one barrier
// per chunk orders reads-before-overwrite (overwrite is 2 barriers later).
__global__ __launch_bounds__(256) void lmmd_main(
    const unsigned short* __restrict__ pack, const float* __restrict__ negc,
    double* __restrict__ accOut) {
  __shared__ __align__(16) unsigned short bufB[2][128][32];  // 16 KB
  __shared__ double dred[256];

  const int t = threadIdx.x;
  const int lane = t & 63;
  const int wv = t >> 6;
  const int bi = blockIdx.x >> 6;
  const int bj = blockIdx.x & 63;
  const int r15 = lane & 15;
  const int kb0 = (lane >> 4) * 8;

  const int rowSi = (bi * 64 + wv * 16 + r15) * KP;
  const int rowTi = rowSi + BN * KP;

  // staging assignment: thread t stages 32 B of the 8 KB chunk panel
  const int srow = t >> 1;                       // 0..127 (0-63 S, 64-127 T)
  const int soff = (t & 1) * 16;                 // short offset within row
  const int srowG = (srow < 64) ? (bj * 64 + srow) : (BN + bj * 64 + (srow - 64));
  const size_t sbase = (size_t)srowG * KP;

  constexpr int koAarr[10] = {0, 32, 64, 96, 128, 160, 192, 224, AUGA, LABK};
  constexpr int koBarr[10] = {0, 32, 64, 96, 128, 160, 192, 224, AUGB, LABK};

  f32x4 aSS[4], aTT[4], aST[4], wSS[4], wTT[4], wST[4];
#pragma unroll
  for (int n = 0; n < 4; ++n) {
    aSS[n] = {0.f, 0.f, 0.f, 0.f};
    aTT[n] = {0.f, 0.f, 0.f, 0.f};
    aST[n] = {0.f, 0.f, 0.f, 0.f};
    wSS[n] = {0.f, 0.f, 0.f, 0.f};
    wTT[n] = {0.f, 0.f, 0.f, 0.f};
    wST[n] = {0.f, 0.f, 0.f, 0.f};
  }

  // prologue: stage chunk 0 into buf 0
  {
    const float4 v0 = *(const float4*)&pack[sbase + koBarr[0] + soff];
    const float4 v1 = *(const float4*)&pack[sbase + koBarr[0] + soff + 8];
    *(float4*)&bufB[0][srow][soff] = v0;
    *(float4*)&bufB[0][srow][soff + 8] = v1;
  }

#pragma unroll
  for (int c = 0; c < 10; ++c) {
    __syncthreads();  // buf[c&1] ready; all reads of buf[(c+1)&1] from c-1 done
    // issue-early: global loads for next chunk's staging
    float4 s0, s1;
    if (c < 9) {
      s0 = *(const float4*)&pack[sbase + koBarr[c + 1] + soff];
      s1 = *(const float4*)&pack[sbase + koBarr[c + 1] + soff + 8];
    }
    // compute chunk c: A from global, B from LDS
    const bf16x8 aS = *(const bf16x8*)&pack[rowSi + koAarr[c] + kb0];
    const bf16x8 aT = *(const bf16x8*)&pack[rowTi + koAarr[c] + kb0];
    const int cb = c & 1;
#pragma unroll
    for (int n = 0; n < 4; ++n) {
      const bf16x8 bS = *(const bf16x8*)&bufB[cb][n * 16 + r15][kb0];
      const bf16x8 bT = *(const bf16x8*)&bufB[cb][64 + n * 16 + r15][kb0];
      if (c < 9) {
        aSS[n] = __builtin_amdgcn_mfma_f32_16x16x32_bf16(aS, bS, aSS[n], 0, 0, 0);
        aTT[n] = __builtin_amdgcn_mfma_f32_16x16x32_bf16(aT, bT, aTT[n], 0, 0, 0);
        aST[n] = __builtin_amdgcn_mfma_f32_16x16x32_bf16(aS, bT, aST[n], 0, 0, 0);
      } else {
        wSS[n] = __builtin_amdgcn_mfma_f32_16x16x32_bf16(aS, bS, wSS[n], 0, 0, 0);
        wTT[n] = __builtin_amdgcn_mfma_f32_16x16x32_bf16(aT, bT, wTT[n], 0, 0, 0);
        wST[n] = __builtin_amdgcn_mfma_f32_16x16x32_bf16(aS, bT, wST[n], 0, 0, 0);
      }
    }
    // write-late: stage next chunk into the other buffer
    if (c < 9) {
      const int nb = (c + 1) & 1;
      *(float4*)&bufB[nb][srow][soff] = s0;
      *(float4*)&bufB[nb][srow][soff + 8] = s1;
    }
  }

  // epilogue: l2 = -2*acc, 5-kernel exp sum, weighted combine (all co-located)
  const float nc0 = negc[0], nc1 = negc[1], nc2 = negc[2], nc3 = negc[3],
              nc4 = negc[4];
  double tsum = 0.0;
#pragma unroll
  for (int n = 0; n < 4; ++n) {
#pragma unroll
    for (int e = 0; e < 4; ++e) {
      const float l2ss = -2.f * aSS[n][e];
      const float l2tt = -2.f * aTT[n][e];
      const float l2st = -2.f * aST[n][e];
      const float Kss = __expf(l2ss * nc0) + __expf(l2ss * nc1) +
                        __expf(l2ss * nc2) + __expf(l2ss * nc3) +
                        __expf(l2ss * nc4);
      const float Ktt = __expf(l2tt * nc0) + __expf(l2tt * nc1) +
                        __expf(l2tt * nc2) + __expf(l2tt * nc3) +
                        __expf(l2tt * nc4);
      const float Kst = __expf(l2st * nc0) + __expf(l2st * nc1) +
                        __expf(l2st * nc2) + __expf(l2st * nc3) +
                        __expf(l2st * nc4);
      tsum += (double)(wSS[n][e] * Kss + wTT[n][e] * Ktt -
                       2.f * wST[n][e] * Kst);
    }
  }
  dred[t] = tsum;
  __syncthreads();
  for (int s = 128; s; s >>= 1) {
    if (t < s) dred[t] += dred[t + s];
    __syncthreads();
  }
  if (t == 0) atomicAdd(accOut, dred[0]);
}

// ---------------- finalize ----------------
__global__ void finalize_kernel(const double* __restrict__ acc,
                                float* __restrict__ out) {
  out[0] = (float)acc[0];
}

extern "C" void kernel_launch(void* const* d_in, const int* in_sizes, int n_in,
                              void* d_out, int out_size, void* d_ws,
                              size_t ws_size, hipStream_t stream) {
  const float* source = (const float*)d_in[0];
  const float* target = (const float*)d_in[1];
  const float* s_label = (const float*)d_in[2];
  const float* t_label = (const float*)d_in[3];

  double* acc = (double*)d_ws;  // [0] loss
  double* sumsq = acc + 1;      // [1]
  double* colsum = acc + 2;     // [2..257]
  float* fbase = (float*)((char*)d_ws + 2112);
  float* aScale = fbase;        // 32
  float* bScale = fbase + 32;   // 32
  float* negc = fbase + 64;     // 8
  unsigned short* pack = (unsigned short*)((char*)d_ws + 4096);  // 8192*352

  hipMemsetAsync(d_ws, 0, 2112, stream);
  colscale_kernel<<<32, 256, 0, stream>>>(s_label, t_label, aScale, bScale);
  stats_kernel<<<256, 256, 0, stream>>>(source, target, colsum, sumsq);
  bw_kernel<<<1, 256, 0, stream>>>(sumsq, colsum, negc);
  pack_kernel<<<8192, 64, 0, stream>>>(source, target, s_label, t_label,
                                       aScale, bScale, pack);
  lmmd_main<<<4096, 256, 0, stream>>>(pack, negc, acc);
  finalize_kernel<<<1, 1, 0, stream>>>(acc, (float*)d_out);
}

// Round 12
// 166.229 us; speedup vs baseline: 4.7785x; 1.0312x over previous
//
#include <hip/hip_runtime.h>
#include <hip/hip_bf16.h>
#include <math.h>

#define BN 4096   // batch per domain
#define DD 256    // feature dim
#define CC 31     // label classes
#define KP 352    // packed k per row: 256 feat + 32 augA + 32 augB + 32 label
#define AUGA 256
#define AUGB 288
#define LABK 320
#define LROW 40   // LDS row pitch in shorts (80 B): banks 20r mod 32 -> 2-way max

typedef __attribute__((ext_vector_type(8))) short bf16x8;
typedef __attribute__((ext_vector_type(4))) float f32x4;

static __device__ inline unsigned short f2bf(float v) {
  __hip_bfloat16 h = __float2bfloat16(v);
  union { __hip_bfloat16 h; unsigned short u; } cv;
  cv.h = h;
  return cv.u;
}
static __device__ inline float bf2f(unsigned short u) {
  return __uint_as_float(((unsigned int)u) << 16);
}

// ---------------- workspace layout ----------------
// [0]        double loss_acc
// [1]        double sum_sq
// [2..257]   double colsum[256]
// [258..289] double labsumS[32]
// [290..321] double labsumT[32]
// byte 2624: float aScale[32], bScale[32], negc[8]
// byte 4096: unsigned short pack[8192][352]   (~5.8 MB)

// ---------------- fused stats: feature colsums + sumsq + label colsums --------
// 256 blocks x 256 threads. Feature part: block b covers rows [b*32,b*32+32),
// thread d = col d (coalesced across threads). Label part: blocks 0..127 cover
// s_label rows [b*32..), blocks 128..255 cover t_label rows; threads 0..30 sum
// one label column over the block's 32 rows.
__global__ void stats_kernel(const float* __restrict__ source,
                             const float* __restrict__ target,
                             const float* __restrict__ s_label,
                             const float* __restrict__ t_label,
                             double* __restrict__ colsum,
                             double* __restrict__ sumsq,
                             double* __restrict__ labsumS,
                             double* __restrict__ labsumT) {
  const int d = threadIdx.x;
  const int r0 = blockIdx.x * 32;
  float cs = 0.f, sq = 0.f;
  for (int r = r0; r < r0 + 32; ++r) {
    const float v = (r < BN) ? source[(size_t)r * DD + d]
                             : target[(size_t)(r - BN) * DD + d];
    cs += v;
    sq += v * v;
  }
  atomicAdd(&colsum[d], (double)cs);
  __shared__ float red[256];
  red[d] = sq;
  __syncthreads();
  for (int s = 128; s; s >>= 1) {
    if (d < s) red[d] += red[d + s];
    __syncthreads();
  }
  if (d == 0) atomicAdd(sumsq, (double)red[0]);

  // label column sums (small: 32x31 per block)
  if (d < CC) {
    const bool isS = (blockIdx.x < 128);
    const int lr0 = (isS ? blockIdx.x : blockIdx.x - 128) * 32;
    const float* lab = isS ? s_label : t_label;
    float ls = 0.f;
    for (int r = lr0; r < lr0 + 32; ++r) ls += lab[(size_t)r * CC + d];
    atomicAdd(isS ? &labsumS[d] : &labsumT[d], (double)ls);
  }
}

// ---------------- bw + scales: one block ----------------
__global__ void bw_scale_kernel(const double* __restrict__ sumsq,
                                const double* __restrict__ colsum,
                                const double* __restrict__ labsumS,
                                const double* __restrict__ labsumT,
                                float* __restrict__ negc,
                                float* __restrict__ aScale,
                                float* __restrict__ bScale) {
  __shared__ double red[256];
  int t = threadIdx.x;
  double cs = colsum[t];
  red[t] = cs * cs;
  __syncthreads();
  for (int s = 128; s; s >>= 1) {
    if (t < s) red[t] += red[t + s];
    __syncthreads();
  }
  if (t == 0) {
    double suml2 = 2.0 * 8192.0 * (*sumsq) - 2.0 * red[0];
    double bw = suml2 / (8192.0 * 8192.0 - 8192.0);
    bw = bw / 4.0;  // KERNEL_MUL^(KERNEL_NUM//2)
    for (int k = 0; k < 5; ++k)
      negc[k] = (float)(-1.0 / (bw * (double)(1 << k)));
  }
  if (t < 32) {
    double s_sum = (t < CC) ? labsumS[t] : 0.0;
    double t_sum = (t < CC) ? labsumT[t] : 0.0;
    bool valid = (t < CC) && (s_sum != 0.0) && (t_sum != 0.0);
    aScale[t] = valid ? (float)(1.0 / s_sum) : 0.f;
    bScale[t] = valid ? (float)(1.0 / t_sum) : 0.f;
  }
}

// ---------------- pack kernel: fp32 -> bf16 rows with aug + labels ----------------
// 2048 blocks x 256 threads; wave (64 threads) per row, 4 rows/block.
// pack[vr][0..255]   = bf16(x)
// pack[vr][256..287] = augA = [h, lo, 1, 1, 0...]   (h+lo ~ -0.5*sum(x_bf16^2))
// pack[vr][288..319] = augB = [1, 1, h, lo, 0...]
// pack[vr][320..351] = scaled label vec (31 + pad0)
// => dot(A_i, B_j): acc = sum(x_i x_j) - 0.5 sq_i - 0.5 sq_j => l2 = -2*acc.
__global__ void pack_kernel(const float* __restrict__ source,
                            const float* __restrict__ target,
                            const float* __restrict__ s_label,
                            const float* __restrict__ t_label,
                            const float* __restrict__ aScale,
                            const float* __restrict__ bScale,
                            unsigned short* __restrict__ pack) {
  const int vr = blockIdx.x * 4 + (threadIdx.x >> 6);  // 0..8191
  const int l = threadIdx.x & 63;
  const bool isS = (vr < BN);
  const float* xp = isS ? (source + (size_t)vr * DD)
                        : (target + (size_t)(vr - BN) * DD);
  float4 v = ((const float4*)xp)[l];
  unsigned short ub[4] = {f2bf(v.x), f2bf(v.y), f2bf(v.z), f2bf(v.w)};
  float f[4];
#pragma unroll
  for (int e = 0; e < 4; ++e) f[e] = bf2f(ub[e]);
  float sq = f[0] * f[0] + f[1] * f[1] + f[2] * f[2] + f[3] * f[3];
#pragma unroll
  for (int off = 32; off; off >>= 1) sq += __shfl_xor(sq, off);

  const size_t rb = (size_t)vr * KP;
  *(short4*)&pack[rb + l * 4] =
      make_short4((short)ub[0], (short)ub[1], (short)ub[2], (short)ub[3]);

  if (l < 8) {
    const unsigned short one = f2bf(1.0f);
    const float hs = -0.5f * sq;
    const unsigned short hh = f2bf(hs);
    const unsigned short lo = f2bf(hs - bf2f(hh));
    const int c0 = l * 4;
    unsigned short a_aug[4], b_aug[4], labv[4];
#pragma unroll
    for (int e = 0; e < 4; ++e) {
      const int c = c0 + e;
      a_aug[e] = (c == 0) ? hh : (c == 1) ? lo : (c <= 3) ? one : (unsigned short)0;
      b_aug[e] = (c <= 1) ? one : (c == 2) ? hh : (c == 3) ? lo : (unsigned short)0;
      float lv = 0.f;
      if (c < CC) {
        lv = isS ? s_label[(size_t)vr * CC + c] * aScale[c]
                 : t_label[(size_t)(vr - BN) * CC + c] * bScale[c];
      }
      labv[e] = f2bf(lv);
    }
    *(short4*)&pack[rb + AUGA + c0] = make_short4(
        (short)a_aug[0], (short)a_aug[1], (short)a_aug[2], (short)a_aug[3]);
    *(short4*)&pack[rb + AUGB + c0] = make_short4(
        (short)b_aug[0], (short)b_aug[1], (short)b_aug[2], (short)b_aug[3]);
    *(short4*)&pack[rb + LABK + c0] = make_short4(
        (short)labv[0], (short)labv[1], (short)labv[2], (short)labv[3]);
  }
}

// ---------------- main fused kernel (MFMA + LDS-staged B, double-buffered) ----
// 64x64 tile per block, 4 waves; wave w owns rows [w*16,w*16+16), all 64 cols.
// B-panel staged once per K-chunk. LDS row pitch 40 shorts (80B): read banks
// 20r mod 32 cover each bank exactly 2x per 16-lane group -> conflict-free.
__global__ __launch_bounds__(256) void lmmd_main(
    const unsigned short* __restrict__ pack, const float* __restrict__ negc,
    double* __restrict__ accOut) {
  __shared__ __align__(16) unsigned short bufB[2][128][LROW];  // 20 KB
  __shared__ double dred[256];

  const int t = threadIdx.x;
  const int lane = t & 63;
  const int wv = t >> 6;
  const int bi = blockIdx.x >> 6;
  const int bj = blockIdx.x & 63;
  const int r15 = lane & 15;
  const int kb0 = (lane >> 4) * 8;

  const int rowSi = (bi * 64 + wv * 16 + r15) * KP;
  const int rowTi = rowSi + BN * KP;

  // staging assignment: thread t stages 32 B of the 8 KB chunk panel
  const int srow = t >> 1;                       // 0..127 (0-63 S, 64-127 T)
  const int soff = (t & 1) * 16;                 // short offset within row
  const int srowG = (srow < 64) ? (bj * 64 + srow) : (BN + bj * 64 + (srow - 64));
  const size_t sbase = (size_t)srowG * KP;

  constexpr int koAarr[10] = {0, 32, 64, 96, 128, 160, 192, 224, AUGA, LABK};
  constexpr int koBarr[10] = {0, 32, 64, 96, 128, 160, 192, 224, AUGB, LABK};

  f32x4 aSS[4], aTT[4], aST[4], wSS[4], wTT[4], wST[4];
#pragma unroll
  for (int n = 0; n < 4; ++n) {
    aSS[n] = {0.f, 0.f, 0.f, 0.f};
    aTT[n] = {0.f, 0.f, 0.f, 0.f};
    aST[n] = {0.f, 0.f, 0.f, 0.f};
    wSS[n] = {0.f, 0.f, 0.f, 0.f};
    wTT[n] = {0.f, 0.f, 0.f, 0.f};
    wST[n] = {0.f, 0.f, 0.f, 0.f};
  }

  // prologue: stage chunk 0 into buf 0
  {
    const float4 v0 = *(const float4*)&pack[sbase + koBarr[0] + soff];
    const float4 v1 = *(const float4*)&pack[sbase + koBarr[0] + soff + 8];
    *(float4*)&bufB[0][srow][soff] = v0;
    *(float4*)&bufB[0][srow][soff + 8] = v1;
  }

#pragma unroll
  for (int c = 0; c < 10; ++c) {
    __syncthreads();  // buf[c&1] ready; all reads of buf[(c+1)&1] from c-1 done
    // issue-early: global loads for next chunk's staging
    float4 s0, s1;
    if (c < 9) {
      s0 = *(const float4*)&pack[sbase + koBarr[c + 1] + soff];
      s1 = *(const float4*)&pack[sbase + koBarr[c + 1] + soff + 8];
    }
    // compute chunk c: A from global, B from LDS
    const bf16x8 aS = *(const bf16x8*)&pack[rowSi + koAarr[c] + kb0];
    const bf16x8 aT = *(const bf16x8*)&pack[rowTi + koAarr[c] + kb0];
    const int cb = c & 1;
#pragma unroll
    for (int n = 0; n < 4; ++n) {
      const bf16x8 bS = *(const bf16x8*)&bufB[cb][n * 16 + r15][kb0];
      const bf16x8 bT = *(const bf16x8*)&bufB[cb][64 + n * 16 + r15][kb0];
      if (c < 9) {
        aSS[n] = __builtin_amdgcn_mfma_f32_16x16x32_bf16(aS, bS, aSS[n], 0, 0, 0);
        aTT[n] = __builtin_amdgcn_mfma_f32_16x16x32_bf16(aT, bT, aTT[n], 0, 0, 0);
        aST[n] = __builtin_amdgcn_mfma_f32_16x16x32_bf16(aS, bT, aST[n], 0, 0, 0);
      } else {
        wSS[n] = __builtin_amdgcn_mfma_f32_16x16x32_bf16(aS, bS, wSS[n], 0, 0, 0);
        wTT[n] = __builtin_amdgcn_mfma_f32_16x16x32_bf16(aT, bT, wTT[n], 0, 0, 0);
        wST[n] = __builtin_amdgcn_mfma_f32_16x16x32_bf16(aS, bT, wST[n], 0, 0, 0);
      }
    }
    // write-late: stage next chunk into the other buffer
    if (c < 9) {
      const int nb = (c + 1) & 1;
      *(float4*)&bufB[nb][srow][soff] = s0;
      *(float4*)&bufB[nb][srow][soff + 8] = s1;
    }
  }

  // epilogue: l2 = -2*acc, 5-kernel exp sum, weighted combine (all co-located)
  const float nc0 = negc[0], nc1 = negc[1], nc2 = negc[2], nc3 = negc[3],
              nc4 = negc[4];
  double tsum = 0.0;
#pragma unroll
  for (int n = 0; n < 4; ++n) {
#pragma unroll
    for (int e = 0; e < 4; ++e) {
      const float l2ss = -2.f * aSS[n][e];
      const float l2tt = -2.f * aTT[n][e];
      const float l2st = -2.f * aST[n][e];
      const float Kss = __expf(l2ss * nc0) + __expf(l2ss * nc1) +
                        __expf(l2ss * nc2) + __expf(l2ss * nc3) +
                        __expf(l2ss * nc4);
      const float Ktt = __expf(l2tt * nc0) + __expf(l2tt * nc1) +
                        __expf(l2tt * nc2) + __expf(l2tt * nc3) +
                        __expf(l2tt * nc4);
      const float Kst = __expf(l2st * nc0) + __expf(l2st * nc1) +
                        __expf(l2st * nc2) + __expf(l2st * nc3) +
                        __expf(l2st * nc4);
      tsum += (double)(wSS[n][e] * Kss + wTT[n][e] * Ktt -
                       2.f * wST[n][e] * Kst);
    }
  }
  dred[t] = tsum;
  __syncthreads();
  for (int s = 128; s; s >>= 1) {
    if (t < s) dred[t] += dred[t + s];
    __syncthreads();
  }
  if (t == 0) atomicAdd(accOut, dred[0]);
}

// ---------------- finalize ----------------
__global__ void finalize_kernel(const double* __restrict__ acc,
                                float* __restrict__ out) {
  out[0] = (float)acc[0];
}

extern "C" void kernel_launch(void* const* d_in, const int* in_sizes, int n_in,
                              void* d_out, int out_size, void* d_ws,
                              size_t ws_size, hipStream_t stream) {
  const float* source = (const float*)d_in[0];
  const float* target = (const float*)d_in[1];
  const float* s_label = (const float*)d_in[2];
  const float* t_label = (const float*)d_in[3];

  double* acc = (double*)d_ws;   // [0] loss
  double* sumsq = acc + 1;       // [1]
  double* colsum = acc + 2;      // [2..257]
  double* labsumS = acc + 258;   // [258..289]
  double* labsumT = acc + 290;   // [290..321]
  float* fbase = (float*)((char*)d_ws + 2624);
  float* aScale = fbase;         // 32
  float* bScale = fbase + 32;    // 32
  float* negc = fbase + 64;      // 8
  unsigned short* pack = (unsigned short*)((char*)d_ws + 4096);  // 8192*352

  hipMemsetAsync(d_ws, 0, 2624, stream);
  stats_kernel<<<256, 256, 0, stream>>>(source, target, s_label, t_label,
                                        colsum, sumsq, labsumS, labsumT);
  bw_scale_kernel<<<1, 256, 0, stream>>>(sumsq, colsum, labsumS, labsumT,
                                         negc, aScale, bScale);
  pack_kernel<<<2048, 256, 0, stream>>>(source, target, s_label, t_label,
                                        aScale, bScale, pack);
  lmmd_main<<<4096, 256, 0, stream>>>(pack, negc, acc);
  finalize_kernel<<<1, 1, 0, stream>>>(acc, (float*)d_out);
}